// Round 6
// baseline (439.427 us; speedup 1.0000x reference)
//
#include <hip/hip_runtime.h>
#include <hip/hip_bf16.h>
#include <hip/hip_cooperative_groups.h>

namespace cg = cooperative_groups;

// GraphSAGE 2-layer on MI355X.
//   h   = relu(mean_agg(x) @ W1l + b1 + x @ W1r)
//   out = mean_agg(h @ W2l) + b2 + h @ W2r          (aggregate AFTER transform: 64ch)
// R2: CSR-gather replaced atomic scatter (2302 -> 387 us).
// R3: bf16 gathers + MFMA bf16 GEMMs (387 -> 253 us).
// R4: bucketed 2-pass CSR build (253 -> 229 us).
// R5: build grid 64 -> 512 (229 -> 216 us).
// R6: memset+hist+scan+scatter+buildB+prep (6 dispatches) fused into ONE
//     cooperative kernel (4 grid.sync), reusing the LDS histogram across
//     phases (one fewer 800K-edge pass). 10 dispatches -> 5.

#define TBLOCK 256
#define MAXBUCK 1024   // supports N <= 262144
#define BUILD_GRID 512 // 2 blocks/CU on 256 CUs -> cooperative-safe

typedef __attribute__((ext_vector_type(8))) short short8;
typedef __attribute__((ext_vector_type(4))) float f32x4;

__device__ __forceinline__ float bf2f(ushort u) {
    union { unsigned int i; float f; } v;
    v.i = (unsigned int)u << 16;
    return v.f;
}
__device__ __forceinline__ ushort f2bf(float f) {  // RTNE
    union { float f; unsigned int u; } v;
    v.f = f;
    unsigned int r = v.u + 0x7fffu + ((v.u >> 16) & 1u);
    return (ushort)(r >> 16);
}

__device__ __forceinline__ int load_src(const int* e, long long i, int E, int is64) {
    return is64 ? e[2 * i] : e[i];
}
__device__ __forceinline__ int load_dst(const int* e, long long i, int E, int is64) {
    return is64 ? e[2 * (long long)E + 2 * i] : e[(long long)E + i];
}

// ===========================================================================
// build_k (cooperative): edge-dtype detect, prep (x->bf16, weight transpose),
// bucket histogram, scan, bucket-grouped packed scatter, per-bucket CSR.
// bucket = dst >> 8 (256 nodes each); packed = src | (dst&255)<<24.
// ===========================================================================
__global__ __launch_bounds__(TBLOCK) void build_k(
    const float* __restrict__ x,
    const float* __restrict__ W1l, const float* __restrict__ W1r,
    const float* __restrict__ W2l, const float* __restrict__ W2r,
    const int* __restrict__ edges, int E, int N, int NBUCK,
    ushort* __restrict__ xb, ushort* __restrict__ wc1, ushort* __restrict__ wc2,
    int* __restrict__ hist, int* __restrict__ baseg, int* __restrict__ cursor,
    unsigned int* __restrict__ packed,
    int* __restrict__ offs, int* __restrict__ degi, float* __restrict__ invdeg,
    int* __restrict__ csr, int n8) {
    cg::grid_group grid = cg::this_grid();
    __shared__ int lh[MAXBUCK];
    __shared__ int lb[MAXBUCK];
    __shared__ int sbad[4];
    const int t = threadIdx.x;
    const int nthreads = gridDim.x * TBLOCK;
    const int gtid = blockIdx.x * TBLOCK + t;

    // ---- per-block edge dtype detect (int64 LE < 2^31 => odd words zero) --
    int bad = 0;
    for (int i = t; i < 2048; i += TBLOCK)
        if (edges[2 * i + 1] != 0) bad = 1;
    unsigned long long bm = __ballot(bad);
    if ((t & 63) == 0) sbad[t >> 6] = (bm != 0) ? 1 : 0;
    __syncthreads();
    const int is64 = (sbad[0] | sbad[1] | sbad[2] | sbad[3]) ? 0 : 1;

    // ---- P0: zero hist + prep xb / wc1 / wc2 ------------------------------
    for (int i = gtid; i < MAXBUCK; i += nthreads) hist[i] = 0;
    for (int i = gtid; i < n8; i += nthreads) {
        const float4* p = (const float4*)x + (size_t)i * 2;
        float4 a = p[0], b = p[1];
        short8 o;
        o[0] = f2bf(a.x); o[1] = f2bf(a.y); o[2] = f2bf(a.z); o[3] = f2bf(a.w);
        o[4] = f2bf(b.x); o[5] = f2bf(b.y); o[6] = f2bf(b.z); o[7] = f2bf(b.w);
        *(short8*)(xb + (size_t)i * 8) = o;
    }
    // wc[((k>>3)*128 + n)*8 + (k&7)] = W[k][n] (chunk-major for MFMA B-frags)
    // wc1: K=256 = [W1l; W1r], N=128.  wc2: K=128, N=128 = [W2l | W2r].
    for (int i = gtid; i < 49152; i += nthreads) {
        if (i < 32768) {
            int j = i & 7;
            int rest = i >> 3;
            int n = rest & 127;
            int k = ((rest >> 7) << 3) | j;
            float w = (k < 128) ? W1l[k * 128 + n] : W1r[(k - 128) * 128 + n];
            wc1[i] = f2bf(w);
        } else {
            int i2 = i - 32768;
            int j = i2 & 7;
            int rest = i2 >> 3;
            int n = rest & 127;
            int k = ((rest >> 7) << 3) | j;
            float w = (n < 64) ? W2l[k * 64 + n] : W2r[k * 64 + (n - 64)];
            wc2[i2] = f2bf(w);
        }
    }
    grid.sync();

    // ---- P1: bucket histogram (LDS local, merged to global) ---------------
    for (int i = t; i < NBUCK; i += TBLOCK) lh[i] = 0;
    __syncthreads();
    const int per = (E + gridDim.x - 1) / gridDim.x;
    const int b0 = blockIdx.x * per, b1 = min(E, b0 + per);
    for (int i = b0 + t; i < b1; i += TBLOCK) {
        int d = load_dst(edges, i, E, is64);
        atomicAdd(&lh[d >> 8], 1);
    }
    __syncthreads();
    for (int i = t; i < NBUCK; i += TBLOCK)
        if (lh[i]) atomicAdd(&hist[i], lh[i]);
    grid.sync();

    // ---- P2: exclusive scan of bucket counts (block 0) --------------------
    if (blockIdx.x == 0) {
        int v[4];
        int sum = 0;
#pragma unroll
        for (int i = 0; i < 4; i++) {
            int idx = t * 4 + i;
            int d = (idx < NBUCK) ? hist[idx] : 0;
            v[i] = sum;
            sum += d;
        }
        lb[t] = sum;
        __syncthreads();
        for (int off = 1; off < TBLOCK; off <<= 1) {
            int xv = (t >= off) ? lb[t - off] : 0;
            __syncthreads();
            lb[t] += xv;
            __syncthreads();
        }
        int excl = (t == 0) ? 0 : lb[t - 1];
#pragma unroll
        for (int i = 0; i < 4; i++) {
            int idx = t * 4 + i;
            if (idx < NBUCK) {
                int b = excl + v[i];
                baseg[idx] = b;
                cursor[idx] = b;
            }
        }
        if (t == TBLOCK - 1) baseg[NBUCK] = lb[TBLOCK - 1];
    }
    grid.sync();

    // ---- P3: packed scatter (lh still holds this block's counts from P1) --
    for (int i = t; i < NBUCK; i += TBLOCK) {
        int c = lh[i];
        lb[i] = c ? atomicAdd(&cursor[i], c) : 0;
        lh[i] = 0;
    }
    __syncthreads();
    for (int i = b0 + t; i < b1; i += TBLOCK) {
        int s = load_src(edges, i, E, is64);
        int d = load_dst(edges, i, E, is64);
        int b = d >> 8;
        int pos = lb[b] + atomicAdd(&lh[b], 1);
        packed[pos] = (unsigned int)s | ((unsigned int)(d & 255) << 24);
    }
    grid.sync();

    // ---- P4: per-bucket CSR finalize (blocks 0..NBUCK-1) ------------------
    const int bucket = blockIdx.x;
    if (bucket < NBUCK) {
        lh[t] = 0;            // cnt
        lh[TBLOCK + t] = 0;   // cur
        __syncthreads();
        int e0 = baseg[bucket], e1 = baseg[bucket + 1];
        for (int i = e0 + t; i < e1; i += TBLOCK)
            atomicAdd(&lh[packed[i] >> 24], 1);
        __syncthreads();
        int mycnt = lh[t];
        lb[t] = mycnt;
        __syncthreads();
        for (int off = 1; off < TBLOCK; off <<= 1) {
            int xv = (t >= off) ? lb[t - off] : 0;
            __syncthreads();
            lb[t] += xv;
            __syncthreads();
        }
        int excl = (t == 0) ? 0 : lb[t - 1];
        int node = bucket * 256 + t;
        if (node < N) {
            offs[node] = e0 + excl;
            degi[node] = mycnt;
            invdeg[node] = 1.0f / fmaxf((float)mycnt, 1.0f);
        }
        __syncthreads();
        lh[t] = excl;         // per-node exclusive base
        __syncthreads();
        for (int i = e0 + t; i < e1; i += TBLOCK) {
            unsigned int p = packed[i];
            int nl = p >> 24;
            int pos = e0 + lh[nl] + atomicAdd(&lh[TBLOCK + nl], 1);
            csr[pos] = (int)(p & 0xFFFFFFu);
        }
    }
}

// ---- gather-aggregate over bf16 features ---------------------------------
// ACCUM=0: outB[n][:] = bf16(invdeg[n] * sum feat[src])      (layer 1, C=128)
// ACCUM=1: outF[n][:] += invdeg[n] * sum feat[src]           (layer 2, C=64)
template <int C, bool ACCUM>
__global__ __launch_bounds__(TBLOCK) void gatherb_k(const ushort* __restrict__ feat,
                                                    const int* __restrict__ csr,
                                                    const int* __restrict__ offs,
                                                    const int* __restrict__ degi,
                                                    const float* __restrict__ invdeg,
                                                    ushort* __restrict__ outB,
                                                    float* __restrict__ outF, int N) {
    constexpr int G = C / 8;                  // lanes per node, 16B bf16x8 each
    constexpr int NPB = TBLOCK / G;
    int n = blockIdx.x * NPB + threadIdx.x / G;
    if (n >= N) return;
    int lane = threadIdx.x % G;
    int c = lane * 8;
    int s0 = offs[n];
    int d = degi[n];
    float acc[8] = {0.f, 0.f, 0.f, 0.f, 0.f, 0.f, 0.f, 0.f};
    for (int base = 0; base < d; base += G) {
        int rem = d - base;
        int my = (lane < rem) ? csr[s0 + base + lane] : 0;
        if (rem >= G) {
#pragma unroll
            for (int j = 0; j < G; j++) {
                int s = __shfl(my, j, G);
                short8 v = *(const short8*)(feat + (size_t)s * C + c);
#pragma unroll
                for (int q = 0; q < 8; q++) acc[q] += bf2f((ushort)v[q]);
            }
        } else {
            for (int j = 0; j < rem; j++) {
                int s = __shfl(my, j, G);
                short8 v = *(const short8*)(feat + (size_t)s * C + c);
#pragma unroll
                for (int q = 0; q < 8; q++) acc[q] += bf2f((ushort)v[q]);
            }
        }
    }
    float sc = invdeg[n];
    if (ACCUM) {
        float* o = outF + (size_t)n * C + c;
        float4 p0 = *(float4*)o;
        float4 p1 = *(float4*)(o + 4);
        p0.x += sc * acc[0]; p0.y += sc * acc[1]; p0.z += sc * acc[2]; p0.w += sc * acc[3];
        p1.x += sc * acc[4]; p1.y += sc * acc[5]; p1.z += sc * acc[6]; p1.w += sc * acc[7];
        *(float4*)o = p0;
        *(float4*)(o + 4) = p1;
    } else {
        short8 o;
#pragma unroll
        for (int q = 0; q < 8; q++) o[q] = f2bf(sc * acc[q]);
        *(short8*)(outB + (size_t)n * C + c) = o;
    }
}

// ---- MFMA bf16 GEMM: [N_rows x KTOT] @ [KTOT x 128] -----------------------
// mfma_f32_16x16x32_bf16 verified layouts (m89/m91):
//   A frag: lane L holds A[m=L&15][k = (L>>4)*8 + j], j=0..7
//   B frag: lane L holds B[k = (L>>4)*8 + j][n=L&15]  (chunk-major sW: 16B reads)
//   C/D:    reg r -> row=(L>>4)*4+r, col=L&15
// EPI=1: outB = bf16(relu(acc + bias[n]))               (h, 128 cols)
// EPI=2: n<64 -> outB=bf16(acc) (t2b); n>=64 -> outF=acc+bias[n-64] (out, fp32)
template <int KTOT, int EPI>
__global__ __launch_bounds__(TBLOCK) void gemm_k(const ushort* __restrict__ A0,
                                                 const ushort* __restrict__ A1,
                                                 const ushort* __restrict__ wc,
                                                 const float* __restrict__ bias,
                                                 ushort* __restrict__ outB,
                                                 float* __restrict__ outF, int N) {
    __shared__ __align__(16) ushort sW[KTOT * 128];
    for (int i = threadIdx.x * 8; i < KTOT * 128; i += TBLOCK * 8)
        *(short8*)&sW[i] = *(const short8*)&wc[i];
    __syncthreads();

    const int wave = threadIdx.x >> 6;
    const int lane = threadIdx.x & 63;
    const int quad = lane >> 4;
    const int l16 = lane & 15;
    const int m0 = (blockIdx.x * 4 + wave) * 32;
    if (m0 >= N) return;

    f32x4 acc[2][8];
#pragma unroll
    for (int t = 0; t < 2; t++)
#pragma unroll
        for (int nt = 0; nt < 8; nt++) acc[t][nt] = (f32x4){0.f, 0.f, 0.f, 0.f};

    const int k0q = quad * 8;
#pragma unroll
    for (int kb = 0; kb < KTOT; kb += 32) {
        int k = kb + k0q;
        const ushort* abase = (KTOT == 256 && k >= 128) ? (A1 + (k - 128)) : (A0 + k);
        short8 a[2];
#pragma unroll
        for (int t = 0; t < 2; t++) {
            int m = m0 + t * 16 + l16;
            if (m > N - 1) m = N - 1;
            a[t] = *(const short8*)(abase + (size_t)m * 128);
        }
#pragma unroll
        for (int nt = 0; nt < 8; nt++) {
            short8 b = *(const short8*)&sW[((k >> 3) * 128 + nt * 16 + l16) * 8];
            acc[0][nt] = __builtin_amdgcn_mfma_f32_16x16x32_bf16(a[0], b, acc[0][nt], 0, 0, 0);
            acc[1][nt] = __builtin_amdgcn_mfma_f32_16x16x32_bf16(a[1], b, acc[1][nt], 0, 0, 0);
        }
    }

#pragma unroll
    for (int t = 0; t < 2; t++) {
#pragma unroll
        for (int r = 0; r < 4; r++) {
            int m = m0 + t * 16 + quad * 4 + r;
            if (m >= N) continue;
#pragma unroll
            for (int nt = 0; nt < 8; nt++) {
                int n = nt * 16 + l16;
                float v = acc[t][nt][r];
                if (EPI == 1) {
                    v = fmaxf(v + bias[n], 0.f);
                    outB[(size_t)m * 128 + n] = f2bf(v);
                } else {
                    if (n < 64) outB[(size_t)m * 64 + n] = f2bf(v);
                    else outF[(size_t)m * 64 + (n - 64)] = v + bias[n - 64];
                }
            }
        }
    }
}

extern "C" void kernel_launch(void* const* d_in, const int* in_sizes, int n_in,
                              void* d_out, int out_size, void* d_ws, size_t ws_size,
                              hipStream_t stream) {
    const float* x = (const float*)d_in[0];
    const int* edges = (const int*)d_in[1];
    const float* W1l = (const float*)d_in[2];
    const float* b1 = (const float*)d_in[3];
    const float* W1r = (const float*)d_in[4];
    const float* W2l = (const float*)d_in[5];
    const float* b2 = (const float*)d_in[6];
    const float* W2r = (const float*)d_in[7];
    float* out = (float*)d_out;

    const int N = in_sizes[0] / 128;   // 50000
    const int E = in_sizes[1] / 2;     // 800000
    const int Na = (N + 63) & ~63;
    const int NBUCK = (N + 255) >> 8;  // 196
    const int n8 = N * 128 / 8;

    // ---- workspace layout (bytes, 256B-aligned regions) ----
    char* WS = (char*)d_ws;
    size_t off = 0;
    auto alloc = [&](size_t bytes) {
        void* p = WS + off;
        off = (off + bytes + 255) & ~(size_t)255;
        return p;
    };
    int* hist = (int*)alloc((size_t)MAXBUCK * 4);
    int* baseg = (int*)alloc((size_t)(MAXBUCK + 1) * 4);
    int* cursor = (int*)alloc((size_t)MAXBUCK * 4);
    int* offs = (int*)alloc((size_t)Na * 4);
    int* degi = (int*)alloc((size_t)Na * 4);
    float* invdeg = (float*)alloc((size_t)Na * 4);
    unsigned int* packed = (unsigned int*)alloc((size_t)E * 4);
    int* csr = (int*)alloc((size_t)E * 4);
    ushort* xb = (ushort*)alloc((size_t)N * 128 * 2);
    ushort* agg1b = (ushort*)alloc((size_t)N * 128 * 2);
    ushort* hb = (ushort*)alloc((size_t)N * 128 * 2);
    ushort* t2b = (ushort*)alloc((size_t)N * 64 * 2);
    ushort* wc1 = (ushort*)alloc(32768 * 2);
    ushort* wc2 = (ushort*)alloc(16384 * 2);

    // ---- one cooperative kernel: detect+prep+hist+scan+scatter+CSR --------
    {
        int E_ = E, N_ = N, NBUCK_ = NBUCK, n8_ = n8;
        void* args[] = {
            (void*)&x, (void*)&W1l, (void*)&W1r, (void*)&W2l, (void*)&W2r,
            (void*)&edges, (void*)&E_, (void*)&N_, (void*)&NBUCK_,
            (void*)&xb, (void*)&wc1, (void*)&wc2,
            (void*)&hist, (void*)&baseg, (void*)&cursor,
            (void*)&packed, (void*)&offs, (void*)&degi, (void*)&invdeg,
            (void*)&csr, (void*)&n8_};
        hipLaunchCooperativeKernel((void*)build_k, dim3(BUILD_GRID), dim3(TBLOCK),
                                   args, 0, stream);
    }

    // layer 1: agg1b = bf16(mean_agg(xb))
    gatherb_k<128, false><<<(N + 15) / 16, TBLOCK, 0, stream>>>(
        xb, csr, offs, degi, invdeg, agg1b, nullptr, N);
    // hb = bf16(relu([agg1b | xb] @ [W1l; W1r] + b1))
    gemm_k<256, 1><<<(N + 127) / 128, TBLOCK, 0, stream>>>(
        agg1b, xb, wc1, b1, hb, nullptr, N);

    // layer 2: t2b = bf16(hb @ W2l); out = hb @ W2r + b2
    gemm_k<128, 2><<<(N + 127) / 128, TBLOCK, 0, stream>>>(
        hb, nullptr, wc2, b2, t2b, out, N);
    // out += mean_agg(t2b)
    gatherb_k<64, true><<<(N + 31) / 32, TBLOCK, 0, stream>>>(
        t2b, csr, offs, degi, invdeg, nullptr, out, N);
}

// Round 7
// 231.859 us; speedup vs baseline: 1.8952x; 1.8952x over previous
//
#include <hip/hip_runtime.h>
#include <hip/hip_bf16.h>

// GraphSAGE 2-layer on MI355X.
//   h   = relu(mean_agg(x) @ W1l + b1 + x @ W1r)
//   out = mean_agg(h @ W2l) + b2 + h @ W2r          (aggregate AFTER transform: 64ch)
// R2: CSR-gather replaced atomic scatter (2302 -> 387 us).
// R3: bf16 gathers + MFMA bf16 GEMMs (387 -> 253 us).
// R4: bucketed 2-pass CSR build (253 -> 229 us).
// R5: build grid 64 -> 512 (229 -> 216 us).
// R6 FAILED: cooperative fusion; grid.sync() costs ~55 us each on 8 XCDs
//     (264 us for a 35 us build chain). Reverted.
// R7: R5 structure, but: per-(bucket,block) counts matrix (non-atomic stores,
//     no memset needed) + 1-block matrix scan -> scatter with ZERO global
//     atomics; prep fused into hist kernel. 10 dispatches -> 8, no grid.sync.

#define TBLOCK 256
#define MAXBUCK 1024   // supports N <= 262144 (scan_k assumes NBUCK <= 256)
#define HGRID 512      // edge-processing blocks (2/CU)

typedef __attribute__((ext_vector_type(8))) short short8;
typedef __attribute__((ext_vector_type(4))) float f32x4;

__device__ __forceinline__ float bf2f(ushort u) {
    union { unsigned int i; float f; } v;
    v.i = (unsigned int)u << 16;
    return v.f;
}
__device__ __forceinline__ ushort f2bf(float f) {  // RTNE
    union { float f; unsigned int u; } v;
    v.f = f;
    unsigned int r = v.u + 0x7fffu + ((v.u >> 16) & 1u);
    return (ushort)(r >> 16);
}

// ---- per-block edge-index dtype detection (int32 vs int64) ----------------
// int64 little-endian with values < 2^31 => every odd int32 word is zero.
__device__ __forceinline__ int block_detect_is64(const int* __restrict__ edges) {
    __shared__ int sbad[4];
    int tid = threadIdx.x;
    int bad = 0;
    for (int i = tid; i < 2048; i += TBLOCK)
        if (edges[2 * i + 1] != 0) bad = 1;
    unsigned long long b = __ballot(bad);
    if ((tid & 63) == 0) sbad[tid >> 6] = (b != 0) ? 1 : 0;
    __syncthreads();
    int flag = (sbad[0] | sbad[1] | sbad[2] | sbad[3]) ? 0 : 1;
    __syncthreads();
    return flag;
}

__device__ __forceinline__ int load_src(const int* e, long long i, int E, int is64) {
    return is64 ? e[2 * i] : e[i];
}
__device__ __forceinline__ int load_dst(const int* e, long long i, int E, int is64) {
    return is64 ? e[2 * (long long)E + 2 * i] : e[(long long)E + i];
}

// ===========================================================================
// histprep_k: blocks [0,HGRID) do the bucket histogram (bucket = dst>>8) and
// store per-block counts NON-ATOMICALLY to counts[j*HGRID + b] (no pre-zero
// needed). Blocks >= HGRID do prep: x -> bf16 xb, weight transpose/concat.
// wc[((k>>3)*128 + n)*8 + (k&7)] = W[k][n] (chunk-major for MFMA B-frags)
// wc1: K=256 = [W1l; W1r], N=128.  wc2: K=128, N=128 = [W2l | W2r].
// ===========================================================================
__global__ __launch_bounds__(TBLOCK) void histprep_k(
    const float* __restrict__ x,
    const float* __restrict__ W1l, const float* __restrict__ W1r,
    const float* __restrict__ W2l, const float* __restrict__ W2r,
    const int* __restrict__ edges, int E, int NBUCK,
    ushort* __restrict__ xb, ushort* __restrict__ wc1, ushort* __restrict__ wc2,
    int* __restrict__ counts, int n8, int nxb) {
    __shared__ int lh[MAXBUCK];
    const int b = blockIdx.x;
    const int t = threadIdx.x;
    if (b < HGRID) {
        const int is64 = block_detect_is64(edges);
        for (int i = t; i < NBUCK; i += TBLOCK) lh[i] = 0;
        __syncthreads();
        const int per = (E + HGRID - 1) / HGRID;
        const int b0 = b * per, b1 = min(E, b0 + per);
        for (int i = b0 + t; i < b1; i += TBLOCK)
            atomicAdd(&lh[load_dst(edges, i, E, is64) >> 8], 1);
        __syncthreads();
        for (int j = t; j < NBUCK; j += TBLOCK)
            counts[j * HGRID + b] = lh[j];
    } else {
        int pb = b - HGRID;
        if (pb < nxb) {
            int i = pb * TBLOCK + t;
            if (i >= n8) return;
            const float4* p = (const float4*)x + (size_t)i * 2;
            float4 a = p[0], bb = p[1];
            short8 o;
            o[0] = f2bf(a.x); o[1] = f2bf(a.y); o[2] = f2bf(a.z); o[3] = f2bf(a.w);
            o[4] = f2bf(bb.x); o[5] = f2bf(bb.y); o[6] = f2bf(bb.z); o[7] = f2bf(bb.w);
            *(short8*)(xb + (size_t)i * 8) = o;
        } else {
            int i = (pb - nxb) * TBLOCK + t;
            if (i < 32768) {
                int j = i & 7;
                int rest = i >> 3;
                int n = rest & 127;
                int k = ((rest >> 7) << 3) | j;
                float w = (k < 128) ? W1l[k * 128 + n] : W1r[(k - 128) * 128 + n];
                wc1[i] = f2bf(w);
            } else if (i < 49152) {
                int i2 = i - 32768;
                int j = i2 & 7;
                int rest = i2 >> 3;
                int n = rest & 127;
                int k = ((rest >> 7) << 3) | j;
                float w = (n < 64) ? W2l[k * 64 + n] : W2r[k * 64 + (n - 64)];
                wc2[i2] = f2bf(w);
            }
        }
    }
}

// ===========================================================================
// scan_k (1 block): colsum counts -> bucket bases (baseg, exclusive), then
// rewrite counts[j][b] IN PLACE as the global start offset of (bucket j,
// block b)'s run. Assumes NBUCK <= 256.
// ===========================================================================
__global__ __launch_bounds__(TBLOCK) void scan_k(int* __restrict__ counts,
                                                 int* __restrict__ baseg, int NBUCK) {
    __shared__ int s[TBLOCK];
    const int t = threadIdx.x;
    int sum = 0;
    if (t < NBUCK) {
        const int* row = counts + (size_t)t * HGRID;
        for (int b = 0; b < HGRID; b++) sum += row[b];
    }
    s[t] = sum;
    __syncthreads();
    for (int off = 1; off < TBLOCK; off <<= 1) {
        int xv = (t >= off) ? s[t - off] : 0;
        __syncthreads();
        s[t] += xv;
        __syncthreads();
    }
    int excl = (t == 0) ? 0 : s[t - 1];
    if (t < NBUCK) {
        baseg[t] = excl;
        if (t == NBUCK - 1) baseg[NBUCK] = s[t];  // total = E
        int* row = counts + (size_t)t * HGRID;
        int run = excl;
        for (int b = 0; b < HGRID; b++) {
            int c = row[b];
            row[b] = run;
            run += c;
        }
    }
}

// ===========================================================================
// scatterA_k: block b reads its start-offset column (no global atomics),
// then writes packed = src | (dst&255)<<24 into contiguous per-bucket runs.
// ===========================================================================
__global__ __launch_bounds__(TBLOCK) void scatterA_k(const int* __restrict__ edges, int E,
                                                     const int* __restrict__ counts,
                                                     unsigned int* __restrict__ packed,
                                                     int NBUCK) {
    const int is64 = block_detect_is64(edges);
    __shared__ int lb[MAXBUCK];
    __shared__ int lh[MAXBUCK];
    const int b = blockIdx.x;
    const int t = threadIdx.x;
    for (int j = t; j < NBUCK; j += TBLOCK) {
        lb[j] = counts[j * HGRID + b];
        lh[j] = 0;
    }
    __syncthreads();
    const int per = (E + HGRID - 1) / HGRID;
    const int b0 = b * per, b1 = min(E, b0 + per);
    for (int i = b0 + t; i < b1; i += TBLOCK) {
        int s = load_src(edges, i, E, is64);
        int d = load_dst(edges, i, E, is64);
        int bk = d >> 8;
        int pos = lb[bk] + atomicAdd(&lh[bk], 1);
        packed[pos] = (unsigned int)s | ((unsigned int)(d & 255) << 24);
    }
}

// ---- per-bucket CSR finalize (one workgroup per bucket) -------------------
__global__ __launch_bounds__(TBLOCK) void buildB_k(const unsigned int* __restrict__ packed,
                                                   const int* __restrict__ baseg,
                                                   int* __restrict__ offs,
                                                   int* __restrict__ degi,
                                                   float* __restrict__ invdeg,
                                                   int* __restrict__ csr, int N) {
    __shared__ int cnt[TBLOCK], scn[TBLOCK], cur[TBLOCK];
    int t = threadIdx.x;
    int bucket = blockIdx.x;
    int e0 = baseg[bucket], e1 = baseg[bucket + 1];
    cnt[t] = 0;
    cur[t] = 0;
    __syncthreads();
    for (int i = e0 + t; i < e1; i += TBLOCK)
        atomicAdd(&cnt[packed[i] >> 24], 1);
    __syncthreads();
    scn[t] = cnt[t];
    __syncthreads();
    for (int off = 1; off < TBLOCK; off <<= 1) {
        int x = (t >= off) ? scn[t - off] : 0;
        __syncthreads();
        scn[t] += x;
        __syncthreads();
    }
    int excl = (t == 0) ? 0 : scn[t - 1];
    int node = bucket * 256 + t;
    if (node < N) {
        offs[node] = e0 + excl;
        degi[node] = cnt[t];
        invdeg[node] = 1.0f / fmaxf((float)cnt[t], 1.0f);
    }
    __syncthreads();
    cnt[t] = excl;               // reuse as per-node exclusive base
    __syncthreads();
    for (int i = e0 + t; i < e1; i += TBLOCK) {
        unsigned int p = packed[i];
        int nl = p >> 24;
        int pos = e0 + cnt[nl] + atomicAdd(&cur[nl], 1);
        csr[pos] = (int)(p & 0xFFFFFFu);
    }
}

// ---- gather-aggregate over bf16 features ---------------------------------
// ACCUM=0: outB[n][:] = bf16(invdeg[n] * sum feat[src])      (layer 1, C=128)
// ACCUM=1: outF[n][:] += invdeg[n] * sum feat[src]           (layer 2, C=64)
template <int C, bool ACCUM>
__global__ __launch_bounds__(TBLOCK) void gatherb_k(const ushort* __restrict__ feat,
                                                    const int* __restrict__ csr,
                                                    const int* __restrict__ offs,
                                                    const int* __restrict__ degi,
                                                    const float* __restrict__ invdeg,
                                                    ushort* __restrict__ outB,
                                                    float* __restrict__ outF, int N) {
    constexpr int G = C / 8;                  // lanes per node, 16B bf16x8 each
    constexpr int NPB = TBLOCK / G;
    int n = blockIdx.x * NPB + threadIdx.x / G;
    if (n >= N) return;
    int lane = threadIdx.x % G;
    int c = lane * 8;
    int s0 = offs[n];
    int d = degi[n];
    float acc[8] = {0.f, 0.f, 0.f, 0.f, 0.f, 0.f, 0.f, 0.f};
    for (int base = 0; base < d; base += G) {
        int rem = d - base;
        int my = (lane < rem) ? csr[s0 + base + lane] : 0;
        if (rem >= G) {
#pragma unroll
            for (int j = 0; j < G; j++) {
                int s = __shfl(my, j, G);
                short8 v = *(const short8*)(feat + (size_t)s * C + c);
#pragma unroll
                for (int q = 0; q < 8; q++) acc[q] += bf2f((ushort)v[q]);
            }
        } else {
            for (int j = 0; j < rem; j++) {
                int s = __shfl(my, j, G);
                short8 v = *(const short8*)(feat + (size_t)s * C + c);
#pragma unroll
                for (int q = 0; q < 8; q++) acc[q] += bf2f((ushort)v[q]);
            }
        }
    }
    float sc = invdeg[n];
    if (ACCUM) {
        float* o = outF + (size_t)n * C + c;
        float4 p0 = *(float4*)o;
        float4 p1 = *(float4*)(o + 4);
        p0.x += sc * acc[0]; p0.y += sc * acc[1]; p0.z += sc * acc[2]; p0.w += sc * acc[3];
        p1.x += sc * acc[4]; p1.y += sc * acc[5]; p1.z += sc * acc[6]; p1.w += sc * acc[7];
        *(float4*)o = p0;
        *(float4*)(o + 4) = p1;
    } else {
        short8 o;
#pragma unroll
        for (int q = 0; q < 8; q++) o[q] = f2bf(sc * acc[q]);
        *(short8*)(outB + (size_t)n * C + c) = o;
    }
}

// ---- MFMA bf16 GEMM: [N_rows x KTOT] @ [KTOT x 128] -----------------------
// mfma_f32_16x16x32_bf16 verified layouts (m89/m91):
//   A frag: lane L holds A[m=L&15][k = (L>>4)*8 + j], j=0..7
//   B frag: lane L holds B[k = (L>>4)*8 + j][n=L&15]  (chunk-major sW: 16B reads)
//   C/D:    reg r -> row=(L>>4)*4+r, col=L&15
// EPI=1: outB = bf16(relu(acc + bias[n]))               (h, 128 cols)
// EPI=2: n<64 -> outB=bf16(acc) (t2b); n>=64 -> outF=acc+bias[n-64] (out, fp32)
template <int KTOT, int EPI>
__global__ __launch_bounds__(TBLOCK) void gemm_k(const ushort* __restrict__ A0,
                                                 const ushort* __restrict__ A1,
                                                 const ushort* __restrict__ wc,
                                                 const float* __restrict__ bias,
                                                 ushort* __restrict__ outB,
                                                 float* __restrict__ outF, int N) {
    __shared__ __align__(16) ushort sW[KTOT * 128];
    for (int i = threadIdx.x * 8; i < KTOT * 128; i += TBLOCK * 8)
        *(short8*)&sW[i] = *(const short8*)&wc[i];
    __syncthreads();

    const int wave = threadIdx.x >> 6;
    const int lane = threadIdx.x & 63;
    const int quad = lane >> 4;
    const int l16 = lane & 15;
    const int m0 = (blockIdx.x * 4 + wave) * 32;
    if (m0 >= N) return;

    f32x4 acc[2][8];
#pragma unroll
    for (int t = 0; t < 2; t++)
#pragma unroll
        for (int nt = 0; nt < 8; nt++) acc[t][nt] = (f32x4){0.f, 0.f, 0.f, 0.f};

    const int k0q = quad * 8;
#pragma unroll
    for (int kb = 0; kb < KTOT; kb += 32) {
        int k = kb + k0q;
        const ushort* abase = (KTOT == 256 && k >= 128) ? (A1 + (k - 128)) : (A0 + k);
        short8 a[2];
#pragma unroll
        for (int t = 0; t < 2; t++) {
            int m = m0 + t * 16 + l16;
            if (m > N - 1) m = N - 1;
            a[t] = *(const short8*)(abase + (size_t)m * 128);
        }
#pragma unroll
        for (int nt = 0; nt < 8; nt++) {
            short8 b = *(const short8*)&sW[((k >> 3) * 128 + nt * 16 + l16) * 8];
            acc[0][nt] = __builtin_amdgcn_mfma_f32_16x16x32_bf16(a[0], b, acc[0][nt], 0, 0, 0);
            acc[1][nt] = __builtin_amdgcn_mfma_f32_16x16x32_bf16(a[1], b, acc[1][nt], 0, 0, 0);
        }
    }

#pragma unroll
    for (int t = 0; t < 2; t++) {
#pragma unroll
        for (int r = 0; r < 4; r++) {
            int m = m0 + t * 16 + quad * 4 + r;
            if (m >= N) continue;
#pragma unroll
            for (int nt = 0; nt < 8; nt++) {
                int n = nt * 16 + l16;
                float v = acc[t][nt][r];
                if (EPI == 1) {
                    v = fmaxf(v + bias[n], 0.f);
                    outB[(size_t)m * 128 + n] = f2bf(v);
                } else {
                    if (n < 64) outB[(size_t)m * 64 + n] = f2bf(v);
                    else outF[(size_t)m * 64 + (n - 64)] = v + bias[n - 64];
                }
            }
        }
    }
}

extern "C" void kernel_launch(void* const* d_in, const int* in_sizes, int n_in,
                              void* d_out, int out_size, void* d_ws, size_t ws_size,
                              hipStream_t stream) {
    const float* x = (const float*)d_in[0];
    const int* edges = (const int*)d_in[1];
    const float* W1l = (const float*)d_in[2];
    const float* b1 = (const float*)d_in[3];
    const float* W1r = (const float*)d_in[4];
    const float* W2l = (const float*)d_in[5];
    const float* b2 = (const float*)d_in[6];
    const float* W2r = (const float*)d_in[7];
    float* out = (float*)d_out;

    const int N = in_sizes[0] / 128;   // 50000
    const int E = in_sizes[1] / 2;     // 800000
    const int Na = (N + 63) & ~63;
    const int NBUCK = (N + 255) >> 8;  // 196 (scan_k assumes <= 256)
    const int n8 = N * 128 / 8;
    const int nxb = (n8 + TBLOCK - 1) / TBLOCK;

    // ---- workspace layout (bytes, 256B-aligned regions) ----
    char* WS = (char*)d_ws;
    size_t off = 0;
    auto alloc = [&](size_t bytes) {
        void* p = WS + off;
        off = (off + bytes + 255) & ~(size_t)255;
        return p;
    };
    int* counts = (int*)alloc((size_t)MAXBUCK * HGRID * 4);  // per-(bucket,block)
    int* baseg = (int*)alloc((size_t)(MAXBUCK + 1) * 4);
    int* offs = (int*)alloc((size_t)Na * 4);
    int* degi = (int*)alloc((size_t)Na * 4);
    float* invdeg = (float*)alloc((size_t)Na * 4);
    unsigned int* packed = (unsigned int*)alloc((size_t)E * 4);
    int* csr = (int*)alloc((size_t)E * 4);
    ushort* xb = (ushort*)alloc((size_t)N * 128 * 2);
    ushort* agg1b = (ushort*)alloc((size_t)N * 128 * 2);
    ushort* hb = (ushort*)alloc((size_t)N * 128 * 2);
    ushort* t2b = (ushort*)alloc((size_t)N * 64 * 2);
    ushort* wc1 = (ushort*)alloc(32768 * 2);
    ushort* wc2 = (ushort*)alloc(16384 * 2);

    // ---- CSR build (no memset, no global atomics) + prep, 4 dispatches ----
    histprep_k<<<HGRID + nxb + 192, TBLOCK, 0, stream>>>(
        x, W1l, W1r, W2l, W2r, edges, E, NBUCK, xb, wc1, wc2, counts, n8, nxb);
    scan_k<<<1, TBLOCK, 0, stream>>>(counts, baseg, NBUCK);
    scatterA_k<<<HGRID, TBLOCK, 0, stream>>>(edges, E, counts, packed, NBUCK);
    buildB_k<<<NBUCK, TBLOCK, 0, stream>>>(packed, baseg, offs, degi, invdeg, csr, N);

    // layer 1: agg1b = bf16(mean_agg(xb))
    gatherb_k<128, false><<<(N + 15) / 16, TBLOCK, 0, stream>>>(
        xb, csr, offs, degi, invdeg, agg1b, nullptr, N);
    // hb = bf16(relu([agg1b | xb] @ [W1l; W1r] + b1))
    gemm_k<256, 1><<<(N + 127) / 128, TBLOCK, 0, stream>>>(
        agg1b, xb, wc1, b1, hb, nullptr, N);

    // layer 2: t2b = bf16(hb @ W2l); out = hb @ W2r + b2
    gemm_k<128, 2><<<(N + 127) / 128, TBLOCK, 0, stream>>>(
        hb, nullptr, wc2, b2, t2b, out, N);
    // out += mean_agg(t2b)
    gatherb_k<64, true><<<(N + 31) / 32, TBLOCK, 0, stream>>>(
        t2b, csr, offs, degi, invdeg, nullptr, out, N);
}

// Round 8
// 194.230 us; speedup vs baseline: 2.2624x; 1.1937x over previous
//
#include <hip/hip_runtime.h>
#include <hip/hip_bf16.h>

// GraphSAGE 2-layer on MI355X.
//   h   = relu(mean_agg(x) @ W1l + b1 + x @ W1r)
//   out = mean_agg(h @ W2l) + b2 + h @ W2r          (aggregate AFTER transform: 64ch)
// R2: CSR-gather replaced atomic scatter (2302 -> 387 us).
// R3: bf16 gathers + MFMA bf16 GEMMs (387 -> 253 us).
// R4: bucketed 2-pass CSR build (253 -> 229 us).
// R5: build grid 64 -> 512 (229 -> 216 us).
// R6 FAILED: cooperative fusion; grid.sync() ~55 us each on 8 XCDs. Reverted.
// R7: zero-atomic counts-matrix build, but 1-block scan_k was serial: 42.6 us.
// R8: scan parallelized: scanA (196 blocks, LDS row scan) + scanB (1 block,
//     bucket-total scan); scatterA adds baseg[j] + local prefix. ~4 dependent
//     global accesses/thread instead of 1024.

#define TBLOCK 256
#define MAXBUCK 1024   // supports N <= 262144 (scanB assumes NBUCK <= 256)
#define HGRID 512      // edge-processing blocks (2/CU)

typedef __attribute__((ext_vector_type(8))) short short8;
typedef __attribute__((ext_vector_type(4))) float f32x4;

__device__ __forceinline__ float bf2f(ushort u) {
    union { unsigned int i; float f; } v;
    v.i = (unsigned int)u << 16;
    return v.f;
}
__device__ __forceinline__ ushort f2bf(float f) {  // RTNE
    union { float f; unsigned int u; } v;
    v.f = f;
    unsigned int r = v.u + 0x7fffu + ((v.u >> 16) & 1u);
    return (ushort)(r >> 16);
}

// ---- per-block edge-index dtype detection (int32 vs int64) ----------------
// int64 little-endian with values < 2^31 => every odd int32 word is zero.
__device__ __forceinline__ int block_detect_is64(const int* __restrict__ edges) {
    __shared__ int sbad[4];
    int tid = threadIdx.x;
    int bad = 0;
    for (int i = tid; i < 2048; i += TBLOCK)
        if (edges[2 * i + 1] != 0) bad = 1;
    unsigned long long b = __ballot(bad);
    if ((tid & 63) == 0) sbad[tid >> 6] = (b != 0) ? 1 : 0;
    __syncthreads();
    int flag = (sbad[0] | sbad[1] | sbad[2] | sbad[3]) ? 0 : 1;
    __syncthreads();
    return flag;
}

__device__ __forceinline__ int load_src(const int* e, long long i, int E, int is64) {
    return is64 ? e[2 * i] : e[i];
}
__device__ __forceinline__ int load_dst(const int* e, long long i, int E, int is64) {
    return is64 ? e[2 * (long long)E + 2 * i] : e[(long long)E + i];
}

// ===========================================================================
// histprep_k: blocks [0,HGRID) do the bucket histogram (bucket = dst>>8) and
// store per-block counts NON-ATOMICALLY to counts[j*HGRID + b] (no pre-zero
// needed). Blocks >= HGRID do prep: x -> bf16 xb, weight transpose/concat.
// wc[((k>>3)*128 + n)*8 + (k&7)] = W[k][n] (chunk-major for MFMA B-frags)
// wc1: K=256 = [W1l; W1r], N=128.  wc2: K=128, N=128 = [W2l | W2r].
// ===========================================================================
__global__ __launch_bounds__(TBLOCK) void histprep_k(
    const float* __restrict__ x,
    const float* __restrict__ W1l, const float* __restrict__ W1r,
    const float* __restrict__ W2l, const float* __restrict__ W2r,
    const int* __restrict__ edges, int E, int NBUCK,
    ushort* __restrict__ xb, ushort* __restrict__ wc1, ushort* __restrict__ wc2,
    int* __restrict__ counts, int n8, int nxb) {
    __shared__ int lh[MAXBUCK];
    const int b = blockIdx.x;
    const int t = threadIdx.x;
    if (b < HGRID) {
        const int is64 = block_detect_is64(edges);
        for (int i = t; i < NBUCK; i += TBLOCK) lh[i] = 0;
        __syncthreads();
        const int per = (E + HGRID - 1) / HGRID;
        const int b0 = b * per, b1 = min(E, b0 + per);
        for (int i = b0 + t; i < b1; i += TBLOCK)
            atomicAdd(&lh[load_dst(edges, i, E, is64) >> 8], 1);
        __syncthreads();
        for (int j = t; j < NBUCK; j += TBLOCK)
            counts[j * HGRID + b] = lh[j];
    } else {
        int pb = b - HGRID;
        if (pb < nxb) {
            int i = pb * TBLOCK + t;
            if (i >= n8) return;
            const float4* p = (const float4*)x + (size_t)i * 2;
            float4 a = p[0], bb = p[1];
            short8 o;
            o[0] = f2bf(a.x); o[1] = f2bf(a.y); o[2] = f2bf(a.z); o[3] = f2bf(a.w);
            o[4] = f2bf(bb.x); o[5] = f2bf(bb.y); o[6] = f2bf(bb.z); o[7] = f2bf(bb.w);
            *(short8*)(xb + (size_t)i * 8) = o;
        } else {
            int i = (pb - nxb) * TBLOCK + t;
            if (i < 32768) {
                int j = i & 7;
                int rest = i >> 3;
                int n = rest & 127;
                int k = ((rest >> 7) << 3) | j;
                float w = (k < 128) ? W1l[k * 128 + n] : W1r[(k - 128) * 128 + n];
                wc1[i] = f2bf(w);
            } else if (i < 49152) {
                int i2 = i - 32768;
                int j = i2 & 7;
                int rest = i2 >> 3;
                int n = rest & 127;
                int k = ((rest >> 7) << 3) | j;
                float w = (n < 64) ? W2l[k * 64 + n] : W2r[k * 64 + (n - 64)];
                wc2[i2] = f2bf(w);
            }
        }
    }
}

// ===========================================================================
// scanA_k: one block per bucket. Parallel exclusive scan of the bucket's
// HGRID per-block counts (2/thread via LDS), rewrite row in place as LOCAL
// exclusive prefixes, write bucket total.
// ===========================================================================
__global__ __launch_bounds__(TBLOCK) void scanA_k(int* __restrict__ counts,
                                                  int* __restrict__ total) {
    __shared__ int s[TBLOCK];
    const int j = blockIdx.x;
    const int t = threadIdx.x;
    int* row = counts + (size_t)j * HGRID;
    int v0 = row[2 * t];
    int v1 = row[2 * t + 1];
    s[t] = v0 + v1;
    __syncthreads();
    for (int off = 1; off < TBLOCK; off <<= 1) {
        int xv = (t >= off) ? s[t - off] : 0;
        __syncthreads();
        s[t] += xv;
        __syncthreads();
    }
    int excl = (t == 0) ? 0 : s[t - 1];
    row[2 * t] = excl;
    row[2 * t + 1] = excl + v0;
    if (t == TBLOCK - 1) total[j] = s[t];
}

// ===========================================================================
// scanB_k (1 block): exclusive scan of NBUCK bucket totals -> baseg.
// Assumes NBUCK <= 256.
// ===========================================================================
__global__ __launch_bounds__(TBLOCK) void scanB_k(const int* __restrict__ total,
                                                  int* __restrict__ baseg, int NBUCK) {
    __shared__ int s[TBLOCK];
    const int t = threadIdx.x;
    int v = (t < NBUCK) ? total[t] : 0;
    s[t] = v;
    __syncthreads();
    for (int off = 1; off < TBLOCK; off <<= 1) {
        int xv = (t >= off) ? s[t - off] : 0;
        __syncthreads();
        s[t] += xv;
        __syncthreads();
    }
    if (t < NBUCK) {
        baseg[t] = (t == 0) ? 0 : s[t - 1];
        if (t == NBUCK - 1) baseg[NBUCK] = s[t];
    }
}

// ===========================================================================
// scatterA_k: block b's start offset for bucket j = baseg[j] + counts[j][b]
// (no global atomics). Writes packed = src | (dst&255)<<24 into contiguous
// per-bucket runs.
// ===========================================================================
__global__ __launch_bounds__(TBLOCK) void scatterA_k(const int* __restrict__ edges, int E,
                                                     const int* __restrict__ counts,
                                                     const int* __restrict__ baseg,
                                                     unsigned int* __restrict__ packed,
                                                     int NBUCK) {
    const int is64 = block_detect_is64(edges);
    __shared__ int lb[MAXBUCK];
    __shared__ int lh[MAXBUCK];
    const int b = blockIdx.x;
    const int t = threadIdx.x;
    for (int j = t; j < NBUCK; j += TBLOCK) {
        lb[j] = baseg[j] + counts[j * HGRID + b];
        lh[j] = 0;
    }
    __syncthreads();
    const int per = (E + HGRID - 1) / HGRID;
    const int b0 = b * per, b1 = min(E, b0 + per);
    for (int i = b0 + t; i < b1; i += TBLOCK) {
        int s = load_src(edges, i, E, is64);
        int d = load_dst(edges, i, E, is64);
        int bk = d >> 8;
        int pos = lb[bk] + atomicAdd(&lh[bk], 1);
        packed[pos] = (unsigned int)s | ((unsigned int)(d & 255) << 24);
    }
}

// ---- per-bucket CSR finalize (one workgroup per bucket) -------------------
__global__ __launch_bounds__(TBLOCK) void buildB_k(const unsigned int* __restrict__ packed,
                                                   const int* __restrict__ baseg,
                                                   int* __restrict__ offs,
                                                   int* __restrict__ degi,
                                                   float* __restrict__ invdeg,
                                                   int* __restrict__ csr, int N) {
    __shared__ int cnt[TBLOCK], scn[TBLOCK], cur[TBLOCK];
    int t = threadIdx.x;
    int bucket = blockIdx.x;
    int e0 = baseg[bucket], e1 = baseg[bucket + 1];
    cnt[t] = 0;
    cur[t] = 0;
    __syncthreads();
    for (int i = e0 + t; i < e1; i += TBLOCK)
        atomicAdd(&cnt[packed[i] >> 24], 1);
    __syncthreads();
    scn[t] = cnt[t];
    __syncthreads();
    for (int off = 1; off < TBLOCK; off <<= 1) {
        int x = (t >= off) ? scn[t - off] : 0;
        __syncthreads();
        scn[t] += x;
        __syncthreads();
    }
    int excl = (t == 0) ? 0 : scn[t - 1];
    int node = bucket * 256 + t;
    if (node < N) {
        offs[node] = e0 + excl;
        degi[node] = cnt[t];
        invdeg[node] = 1.0f / fmaxf((float)cnt[t], 1.0f);
    }
    __syncthreads();
    cnt[t] = excl;               // reuse as per-node exclusive base
    __syncthreads();
    for (int i = e0 + t; i < e1; i += TBLOCK) {
        unsigned int p = packed[i];
        int nl = p >> 24;
        int pos = e0 + cnt[nl] + atomicAdd(&cur[nl], 1);
        csr[pos] = (int)(p & 0xFFFFFFu);
    }
}

// ---- gather-aggregate over bf16 features ---------------------------------
// ACCUM=0: outB[n][:] = bf16(invdeg[n] * sum feat[src])      (layer 1, C=128)
// ACCUM=1: outF[n][:] += invdeg[n] * sum feat[src]           (layer 2, C=64)
template <int C, bool ACCUM>
__global__ __launch_bounds__(TBLOCK) void gatherb_k(const ushort* __restrict__ feat,
                                                    const int* __restrict__ csr,
                                                    const int* __restrict__ offs,
                                                    const int* __restrict__ degi,
                                                    const float* __restrict__ invdeg,
                                                    ushort* __restrict__ outB,
                                                    float* __restrict__ outF, int N) {
    constexpr int G = C / 8;                  // lanes per node, 16B bf16x8 each
    constexpr int NPB = TBLOCK / G;
    int n = blockIdx.x * NPB + threadIdx.x / G;
    if (n >= N) return;
    int lane = threadIdx.x % G;
    int c = lane * 8;
    int s0 = offs[n];
    int d = degi[n];
    float acc[8] = {0.f, 0.f, 0.f, 0.f, 0.f, 0.f, 0.f, 0.f};
    for (int base = 0; base < d; base += G) {
        int rem = d - base;
        int my = (lane < rem) ? csr[s0 + base + lane] : 0;
        if (rem >= G) {
#pragma unroll
            for (int j = 0; j < G; j++) {
                int s = __shfl(my, j, G);
                short8 v = *(const short8*)(feat + (size_t)s * C + c);
#pragma unroll
                for (int q = 0; q < 8; q++) acc[q] += bf2f((ushort)v[q]);
            }
        } else {
            for (int j = 0; j < rem; j++) {
                int s = __shfl(my, j, G);
                short8 v = *(const short8*)(feat + (size_t)s * C + c);
#pragma unroll
                for (int q = 0; q < 8; q++) acc[q] += bf2f((ushort)v[q]);
            }
        }
    }
    float sc = invdeg[n];
    if (ACCUM) {
        float* o = outF + (size_t)n * C + c;
        float4 p0 = *(float4*)o;
        float4 p1 = *(float4*)(o + 4);
        p0.x += sc * acc[0]; p0.y += sc * acc[1]; p0.z += sc * acc[2]; p0.w += sc * acc[3];
        p1.x += sc * acc[4]; p1.y += sc * acc[5]; p1.z += sc * acc[6]; p1.w += sc * acc[7];
        *(float4*)o = p0;
        *(float4*)(o + 4) = p1;
    } else {
        short8 o;
#pragma unroll
        for (int q = 0; q < 8; q++) o[q] = f2bf(sc * acc[q]);
        *(short8*)(outB + (size_t)n * C + c) = o;
    }
}

// ---- MFMA bf16 GEMM: [N_rows x KTOT] @ [KTOT x 128] -----------------------
// mfma_f32_16x16x32_bf16 verified layouts (m89/m91):
//   A frag: lane L holds A[m=L&15][k = (L>>4)*8 + j], j=0..7
//   B frag: lane L holds B[k = (L>>4)*8 + j][n=L&15]  (chunk-major sW: 16B reads)
//   C/D:    reg r -> row=(L>>4)*4+r, col=L&15
// EPI=1: outB = bf16(relu(acc + bias[n]))               (h, 128 cols)
// EPI=2: n<64 -> outB=bf16(acc) (t2b); n>=64 -> outF=acc+bias[n-64] (out, fp32)
template <int KTOT, int EPI>
__global__ __launch_bounds__(TBLOCK) void gemm_k(const ushort* __restrict__ A0,
                                                 const ushort* __restrict__ A1,
                                                 const ushort* __restrict__ wc,
                                                 const float* __restrict__ bias,
                                                 ushort* __restrict__ outB,
                                                 float* __restrict__ outF, int N) {
    __shared__ __align__(16) ushort sW[KTOT * 128];
    for (int i = threadIdx.x * 8; i < KTOT * 128; i += TBLOCK * 8)
        *(short8*)&sW[i] = *(const short8*)&wc[i];
    __syncthreads();

    const int wave = threadIdx.x >> 6;
    const int lane = threadIdx.x & 63;
    const int quad = lane >> 4;
    const int l16 = lane & 15;
    const int m0 = (blockIdx.x * 4 + wave) * 32;
    if (m0 >= N) return;

    f32x4 acc[2][8];
#pragma unroll
    for (int t = 0; t < 2; t++)
#pragma unroll
        for (int nt = 0; nt < 8; nt++) acc[t][nt] = (f32x4){0.f, 0.f, 0.f, 0.f};

    const int k0q = quad * 8;
#pragma unroll
    for (int kb = 0; kb < KTOT; kb += 32) {
        int k = kb + k0q;
        const ushort* abase = (KTOT == 256 && k >= 128) ? (A1 + (k - 128)) : (A0 + k);
        short8 a[2];
#pragma unroll
        for (int t = 0; t < 2; t++) {
            int m = m0 + t * 16 + l16;
            if (m > N - 1) m = N - 1;
            a[t] = *(const short8*)(abase + (size_t)m * 128);
        }
#pragma unroll
        for (int nt = 0; nt < 8; nt++) {
            short8 b = *(const short8*)&sW[((k >> 3) * 128 + nt * 16 + l16) * 8];
            acc[0][nt] = __builtin_amdgcn_mfma_f32_16x16x32_bf16(a[0], b, acc[0][nt], 0, 0, 0);
            acc[1][nt] = __builtin_amdgcn_mfma_f32_16x16x32_bf16(a[1], b, acc[1][nt], 0, 0, 0);
        }
    }

#pragma unroll
    for (int t = 0; t < 2; t++) {
#pragma unroll
        for (int r = 0; r < 4; r++) {
            int m = m0 + t * 16 + quad * 4 + r;
            if (m >= N) continue;
#pragma unroll
            for (int nt = 0; nt < 8; nt++) {
                int n = nt * 16 + l16;
                float v = acc[t][nt][r];
                if (EPI == 1) {
                    v = fmaxf(v + bias[n], 0.f);
                    outB[(size_t)m * 128 + n] = f2bf(v);
                } else {
                    if (n < 64) outB[(size_t)m * 64 + n] = f2bf(v);
                    else outF[(size_t)m * 64 + (n - 64)] = v + bias[n - 64];
                }
            }
        }
    }
}

extern "C" void kernel_launch(void* const* d_in, const int* in_sizes, int n_in,
                              void* d_out, int out_size, void* d_ws, size_t ws_size,
                              hipStream_t stream) {
    const float* x = (const float*)d_in[0];
    const int* edges = (const int*)d_in[1];
    const float* W1l = (const float*)d_in[2];
    const float* b1 = (const float*)d_in[3];
    const float* W1r = (const float*)d_in[4];
    const float* W2l = (const float*)d_in[5];
    const float* b2 = (const float*)d_in[6];
    const float* W2r = (const float*)d_in[7];
    float* out = (float*)d_out;

    const int N = in_sizes[0] / 128;   // 50000
    const int E = in_sizes[1] / 2;     // 800000
    const int Na = (N + 63) & ~63;
    const int NBUCK = (N + 255) >> 8;  // 196 (scanB assumes <= 256)
    const int n8 = N * 128 / 8;
    const int nxb = (n8 + TBLOCK - 1) / TBLOCK;

    // ---- workspace layout (bytes, 256B-aligned regions) ----
    char* WS = (char*)d_ws;
    size_t off = 0;
    auto alloc = [&](size_t bytes) {
        void* p = WS + off;
        off = (off + bytes + 255) & ~(size_t)255;
        return p;
    };
    int* counts = (int*)alloc((size_t)MAXBUCK * HGRID * 4);  // per-(bucket,block)
    int* total = (int*)alloc((size_t)MAXBUCK * 4);
    int* baseg = (int*)alloc((size_t)(MAXBUCK + 1) * 4);
    int* offs = (int*)alloc((size_t)Na * 4);
    int* degi = (int*)alloc((size_t)Na * 4);
    float* invdeg = (float*)alloc((size_t)Na * 4);
    unsigned int* packed = (unsigned int*)alloc((size_t)E * 4);
    int* csr = (int*)alloc((size_t)E * 4);
    ushort* xb = (ushort*)alloc((size_t)N * 128 * 2);
    ushort* agg1b = (ushort*)alloc((size_t)N * 128 * 2);
    ushort* hb = (ushort*)alloc((size_t)N * 128 * 2);
    ushort* t2b = (ushort*)alloc((size_t)N * 64 * 2);
    ushort* wc1 = (ushort*)alloc(32768 * 2);
    ushort* wc2 = (ushort*)alloc(16384 * 2);

    // ---- CSR build (no memset, no global atomics) + prep -----------------
    histprep_k<<<HGRID + nxb + 192, TBLOCK, 0, stream>>>(
        x, W1l, W1r, W2l, W2r, edges, E, NBUCK, xb, wc1, wc2, counts, n8, nxb);
    scanA_k<<<NBUCK, TBLOCK, 0, stream>>>(counts, total);
    scanB_k<<<1, TBLOCK, 0, stream>>>(total, baseg, NBUCK);
    scatterA_k<<<HGRID, TBLOCK, 0, stream>>>(edges, E, counts, baseg, packed, NBUCK);
    buildB_k<<<NBUCK, TBLOCK, 0, stream>>>(packed, baseg, offs, degi, invdeg, csr, N);

    // layer 1: agg1b = bf16(mean_agg(xb))
    gatherb_k<128, false><<<(N + 15) / 16, TBLOCK, 0, stream>>>(
        xb, csr, offs, degi, invdeg, agg1b, nullptr, N);
    // hb = bf16(relu([agg1b | xb] @ [W1l; W1r] + b1))
    gemm_k<256, 1><<<(N + 127) / 128, TBLOCK, 0, stream>>>(
        agg1b, xb, wc1, b1, hb, nullptr, N);

    // layer 2: t2b = bf16(hb @ W2l); out = hb @ W2r + b2
    gemm_k<128, 2><<<(N + 127) / 128, TBLOCK, 0, stream>>>(
        hb, nullptr, wc2, b2, t2b, out, N);
    // out += mean_agg(t2b)
    gatherb_k<64, true><<<(N + 31) / 32, TBLOCK, 0, stream>>>(
        t2b, csr, offs, degi, invdeg, nullptr, out, N);
}